// Round 3
// baseline (222.147 us; speedup 1.0000x reference)
//
#include <hip/hip_runtime.h>
#include <cstdint>
#include <cstddef>

// Problem constants
constexpr int B = 64, S = 2048, H = 512, E = 256, V = 32000;
constexpr int NCHUNK = 64;   // attention: 64 chunks of 32 keys per batch

// ---------------------------------------------------------------------------
// Kernel 1: fused scores + online-softmax partials (enc read exactly once).
// One wave per (b, 32-key chunk). Lane = (key-in-batch kb = lane>>4,
// dim-group g = lane&15). Each batch processes 4 keys simultaneously:
// 8 independent float4 loads per lane, 4-step intra-key shuffle reduce,
// 2-step cross-key max — 6 shuffles per 4 keys (vs 6 per key before).
// ---------------------------------------------------------------------------
__global__ __launch_bounds__(256) void attn_part_kernel(
    const float* __restrict__ hd, const float* __restrict__ enc,
    float* __restrict__ m_part, float* __restrict__ l_part,
    float* __restrict__ acc_part)
{
    int b = blockIdx.x >> 4;
    int wave = threadIdx.x >> 6, lane = threadIdx.x & 63;
    int chunk = ((blockIdx.x & 15) << 2) + wave;   // 0..63
    int s0 = chunk * 32;
    int g  = lane & 15;     // dim group: covers d = 64*j + g*4, j = 0..7
    int kb = lane >> 4;     // key within batch of 4

    const float* hb = hd + (size_t)b * H;
    float4 hF[8];
#pragma unroll
    for (int j = 0; j < 8; ++j)
        hF[j] = *(const float4*)(hb + 64 * j + g * 4);

    const float* eb = enc + (size_t)b * S * H;

    float m = -1e30f, l = 0.f;
    float4 acc[8];
#pragma unroll
    for (int j = 0; j < 8; ++j) acc[j] = make_float4(0.f, 0.f, 0.f, 0.f);

    for (int it = 0; it < 8; ++it) {
        const float* kp = eb + (size_t)(s0 + it * 4 + kb) * H + g * 4;
        float4 e[8];
#pragma unroll
        for (int j = 0; j < 8; ++j)
            e[j] = *(const float4*)(kp + 64 * j);

        float p = 0.f;
#pragma unroll
        for (int j = 0; j < 8; ++j)
            p += e[j].x * hF[j].x + e[j].y * hF[j].y
               + e[j].z * hF[j].z + e[j].w * hF[j].w;
        // reduce over the 16 lanes of this key
        p += __shfl_xor(p, 1, 64);
        p += __shfl_xor(p, 2, 64);
        p += __shfl_xor(p, 4, 64);
        p += __shfl_xor(p, 8, 64);
        // max over the 4 keys of this batch (wave-uniform result)
        float bm = p;
        bm = fmaxf(bm, __shfl_xor(bm, 16, 64));
        bm = fmaxf(bm, __shfl_xor(bm, 32, 64));

        if (bm <= m) {              // running max unchanged (wave-uniform branch)
            float w = __expf(p - m);
            float ws = w;
            ws += __shfl_xor(ws, 16, 64);
            ws += __shfl_xor(ws, 32, 64);
            l += ws;
#pragma unroll
            for (int j = 0; j < 8; ++j) {
                acc[j].x += w * e[j].x; acc[j].y += w * e[j].y;
                acc[j].z += w * e[j].z; acc[j].w += w * e[j].w;
            }
        } else {
            float sc = __expf(m - bm);
            m = bm;
            float w = __expf(p - bm);
            float ws = w;
            ws += __shfl_xor(ws, 16, 64);
            ws += __shfl_xor(ws, 32, 64);
            l = l * sc + ws;
#pragma unroll
            for (int j = 0; j < 8; ++j) {
                acc[j].x = acc[j].x * sc + w * e[j].x;
                acc[j].y = acc[j].y * sc + w * e[j].y;
                acc[j].z = acc[j].z * sc + w * e[j].z;
                acc[j].w = acc[j].w * sc + w * e[j].w;
            }
        }
    }

    // sum accumulators across the 4 key-groups (once per chunk)
    float* af = (float*)acc;
#pragma unroll
    for (int q = 0; q < 32; ++q) {
        af[q] += __shfl_xor(af[q], 16, 64);
        af[q] += __shfl_xor(af[q], 32, 64);
    }

    int base = b * NCHUNK + chunk;
    if (lane == 0) { m_part[base] = m; l_part[base] = l; }
    float* ap = acc_part + (size_t)base * H;
    int q = lane >> 4;   // each 16-lane group writes 2 of the 8 j-slices
    *(float4*)(ap + 64 * (2 * q)     + g * 4) = acc[2 * q];
    *(float4*)(ap + 64 * (2 * q + 1) + g * 4) = acc[2 * q + 1];
}

// ---------------------------------------------------------------------------
// Kernel 2: combine partials -> ctx; embedding gather; build transposed LSTM
// input inp_t[k][b], k in [0,1280): [0,256)=xe, [256,768)=ctx, [768,1280)=h0.
// ---------------------------------------------------------------------------
__global__ __launch_bounds__(256) void combine_kernel(
    const float* __restrict__ m_part, const float* __restrict__ l_part,
    const float* __restrict__ acc_part, const int* __restrict__ x,
    const float* __restrict__ emb, const float* __restrict__ h0,
    float* __restrict__ inp_t)
{
    int b = blockIdx.x, t = threadIdx.x;
    float M = -1e30f;
    for (int i = 0; i < NCHUNK; ++i) M = fmaxf(M, m_part[b * NCHUNK + i]);
    float L = 0.f;
    for (int i = 0; i < NCHUNK; ++i)
        L += l_part[b * NCHUNK + i] * __expf(m_part[b * NCHUNK + i] - M);
    float invL = 1.f / L;

    for (int d = t; d < H; d += 256) {
        float s = 0.f;
        for (int i = 0; i < NCHUNK; ++i)
            s += __expf(m_part[b * NCHUNK + i] - M) *
                 acc_part[((size_t)(b * NCHUNK + i)) * H + d];
        inp_t[(E + d) * B + b] = s * invL;
    }
    inp_t[t * B + b] = emb[(size_t)x[b] * E + t];
    for (int d = t; d < H; d += 256)
        inp_t[(E + H + d) * B + b] = h0[b * H + d];
}

// ---------------------------------------------------------------------------
// Tiled fp32 GEMM: C[M][64] = A[M][K] (row-major) * X[K][64].
// 512 threads; tile BM x 64, BK=32. A staged transposed in LDS ([32][BM+4]);
// X staged [32][64]. Per-thread TM x TN micro-tile (TN=2 -> float2 X reads,
// TN=4 -> float4). All global weight traffic is coalesced float4 loads.
// Supports 2-matrix concatenated-K input (LSTM layer 1: w_ih1 | w_hh1).
// WMODE 0: write split-K partial P[ck][M][64].
// WMODE 1: write final transposed C[b][ldc] with bias (fc logits).
// ---------------------------------------------------------------------------
template<int BM, int TM, int TN, int WMODE>
__global__ __launch_bounds__(512) void gemm_kernel(
    const float* __restrict__ A1, int lda1, int nck1,
    const float* __restrict__ A2, int lda2,
    const float* __restrict__ X,
    float* __restrict__ outp,
    const float* __restrict__ bias,
    int m_tiles, int M, int KC, int ldc)
{
    constexpr int NTX = 64 / TN;                 // column groups
    __shared__ float As[32][BM + 4];
    __shared__ float Xs[32][64];

    int mt = blockIdx.x % m_tiles;
    int ck = blockIdx.x / m_tiles;
    int t = threadIdx.x;
    int tx = t % NTX, ty = t / NTX;

    const float* A; int lda; int kA0;
    if (ck < nck1) { A = A1; lda = lda1; kA0 = ck * KC; }
    else           { A = A2; lda = lda2; kA0 = ck * KC - nck1 * KC; }
    int kX0 = ck * KC;
    int m_base = mt * BM;

    float acc[TM][TN];
#pragma unroll
    for (int i = 0; i < TM; ++i)
#pragma unroll
        for (int j = 0; j < TN; ++j) acc[i][j] = 0.f;

    for (int k0 = 0; k0 < KC; k0 += 32) {
        {   // stage X tile: 32x64 floats, one float4 per thread
            int kx = t >> 4, bq = t & 15;
            *(float4*)&Xs[kx][bq * 4] =
                *(const float4*)&X[(size_t)(kX0 + k0 + kx) * 64 + bq * 4];
        }
        {   // stage A tile transposed: BM rows x 32 k
            int kq = t & 7, r = t >> 3;   // r in 0..63
#pragma unroll
            for (int rr = 0; rr < BM / 64; ++rr) {
                int row = r + rr * 64;
                float4 v = *(const float4*)&A[(size_t)(m_base + row) * lda + kA0 + k0 + kq * 4];
                As[kq * 4 + 0][row] = v.x;
                As[kq * 4 + 1][row] = v.y;
                As[kq * 4 + 2][row] = v.z;
                As[kq * 4 + 3][row] = v.w;
            }
        }
        __syncthreads();

#pragma unroll 4
        for (int k = 0; k < 32; ++k) {
            float a[TM];
#pragma unroll
            for (int i = 0; i < TM; i += 4)
                *(float4*)&a[i] = *(const float4*)&As[k][ty * TM + i];
            float xv[TN];
            if constexpr (TN == 2)
                *(float2*)&xv[0] = *(const float2*)&Xs[k][tx * 2];
            else
                *(float4*)&xv[0] = *(const float4*)&Xs[k][tx * 4];
#pragma unroll
            for (int i = 0; i < TM; ++i)
#pragma unroll
                for (int j = 0; j < TN; ++j)
                    acc[i][j] += a[i] * xv[j];
        }
        __syncthreads();
    }

    if constexpr (WMODE == 0) {
        float* P = outp + (size_t)ck * M * 64;
#pragma unroll
        for (int i = 0; i < TM; ++i) {
            if constexpr (TN == 2) {
                float2 v = make_float2(acc[i][0], acc[i][1]);
                *(float2*)&P[(size_t)(m_base + ty * TM + i) * 64 + tx * 2] = v;
            } else {
                float4 v = make_float4(acc[i][0], acc[i][1], acc[i][2], acc[i][3]);
                *(float4*)&P[(size_t)(m_base + ty * TM + i) * 64 + tx * 4] = v;
            }
        }
    } else {
#pragma unroll
        for (int j = 0; j < TN; ++j) {
            int b = tx * TN + j;
#pragma unroll
            for (int i = 0; i < TM; i += 4) {
                int v0 = m_base + ty * TM + i;
                float4 v;
                v.x = acc[i + 0][j] + bias[v0 + 0];
                v.y = acc[i + 1][j] + bias[v0 + 1];
                v.z = acc[i + 2][j] + bias[v0 + 2];
                v.w = acc[i + 3][j] + bias[v0 + 3];
                *(float4*)&outp[(size_t)b * ldc + v0] = v;
            }
        }
    }
}

// ---------------------------------------------------------------------------
// Gate combine + activation: sums split-K partials, adds biases, applies LSTM
// nonlinearity. h written [H][B] (transposed, for next GEMM's X); optional
// [B][H] h/c outputs for the final layer.
// ---------------------------------------------------------------------------
__global__ __launch_bounds__(256) void lstm_act_kernel(
    const float* __restrict__ P, int nck,
    const float* __restrict__ b_ih, const float* __restrict__ b_hh,
    const float* __restrict__ c_prev,
    float* __restrict__ h_t,
    float* __restrict__ out_h, float* __restrict__ out_c)
{
    int idx = blockIdx.x * 256 + threadIdx.x;    // 32768 = H*B
    int b = idx & 63, j = idx >> 6;
    float g[4];
#pragma unroll
    for (int gg = 0; gg < 4; ++gg) {
        int row = j + 512 * gg;
        float s = b_ih[row] + b_hh[row];
        for (int c = 0; c < nck; ++c)
            s += P[((size_t)c * 2048 + row) * 64 + b];
        g[gg] = s;
    }
    float iv = 1.f / (1.f + expf(-g[0]));
    float fv = 1.f / (1.f + expf(-g[1]));
    float gv = tanhf(g[2]);
    float ov = 1.f / (1.f + expf(-g[3]));
    float cp = c_prev ? c_prev[b * H + j] : 0.f;
    float c2 = fv * cp + iv * gv;
    float hv = ov * tanhf(c2);
    h_t[j * B + b] = hv;
    if (out_h) { out_h[b * H + j] = hv; out_c[b * H + j] = c2; }
}

// ---------------------------------------------------------------------------
extern "C" void kernel_launch(void* const* d_in, const int* in_sizes, int n_in,
                              void* d_out, int out_size, void* d_ws, size_t ws_size,
                              hipStream_t stream)
{
    const int*   x     = (const int*)d_in[0];
    const float* hdec  = (const float*)d_in[1];
    const float* enc   = (const float*)d_in[2];
    const float* h0    = (const float*)d_in[3];
    const float* c0    = (const float*)d_in[4];
    const float* emb   = (const float*)d_in[5];
    const float* w_ih1 = (const float*)d_in[6];
    const float* w_hh1 = (const float*)d_in[7];
    const float* b_ih1 = (const float*)d_in[8];
    const float* b_hh1 = (const float*)d_in[9];
    const float* w_ih  = (const float*)d_in[10];
    // d_in[11] = w_hh: multiplied by zero hidden state in layers 2-4 -> skipped
    const float* b_ih  = (const float*)d_in[12];
    const float* b_hh  = (const float*)d_in[13];
    const float* fc_w  = (const float*)d_in[14];
    const float* fc_b  = (const float*)d_in[15];

    float* out = (float*)d_out;
    float* ws  = (float*)d_ws;

    // ws layout (floats), all offsets 16B-aligned
    float* m_part   = ws;                                // 4096
    float* l_part   = ws + 4096;                         // 4096
    float* acc_part = ws + 8192;                         // 64*64*512 = 2097152
    float* inp_t    = acc_part + (size_t)B * NCHUNK * H; // 1280*64
    float* zA       = inp_t + 1280 * B;                  // 512*64
    float* zB       = zA + H * B;                        // 512*64
    float* P        = zB + H * B;                        // 10*2048*64

    float* out_h = out + (size_t)B * V;
    float* out_c = out_h + (size_t)B * H;

    // 1) attention (enc read once, 268 MB); 1024 blocks -> 16 waves/CU
    attn_part_kernel<<<1024, 256, 0, stream>>>(hdec, enc, m_part, l_part, acc_part);
    combine_kernel<<<64, 256, 0, stream>>>(m_part, l_part, acc_part, x, emb, h0, inp_t);

    // 2) LSTM layer 1: gates = [w_ih1 | w_hh1] @ inp_t (K = 1280), KC=128
    gemm_kernel<64, 4, 2, 0><<<320, 512, 0, stream>>>(
        w_ih1, 768, 6, w_hh1, 512, inp_t, P, nullptr, 32, 2048, 128, 0);
    lstm_act_kernel<<<128, 256, 0, stream>>>(P, 10, b_ih1, b_hh1, c0, zA,
                                             nullptr, nullptr);

    // 3) LSTM layers 2-4 (zero h/c: only w_ih contributes), K=512, KC=128
    gemm_kernel<64, 4, 2, 0><<<128, 512, 0, stream>>>(
        w_ih + 0 * (size_t)2048 * H, 512, 4, nullptr, 0, zA, P, nullptr, 32, 2048, 128, 0);
    lstm_act_kernel<<<128, 256, 0, stream>>>(P, 4, b_ih + 0 * 2048, b_hh + 0 * 2048,
                                             nullptr, zB, nullptr, nullptr);

    gemm_kernel<64, 4, 2, 0><<<128, 512, 0, stream>>>(
        w_ih + 1 * (size_t)2048 * H, 512, 4, nullptr, 0, zB, P, nullptr, 32, 2048, 128, 0);
    lstm_act_kernel<<<128, 256, 0, stream>>>(P, 4, b_ih + 1 * 2048, b_hh + 1 * 2048,
                                             nullptr, zA, nullptr, nullptr);

    gemm_kernel<64, 4, 2, 0><<<128, 512, 0, stream>>>(
        w_ih + 2 * (size_t)2048 * H, 512, 4, nullptr, 0, zA, P, nullptr, 32, 2048, 128, 0);
    lstm_act_kernel<<<128, 256, 0, stream>>>(P, 4, b_ih + 2 * 2048, b_hh + 2 * 2048,
                                             nullptr, zB, out_h, out_c);

    // 4) logits = zB^T @ fc_w^T + fc_b, written [b][V] directly (TN=4)
    gemm_kernel<128, 4, 4, 1><<<250, 512, 0, stream>>>(
        fc_w, 512, 1, nullptr, 0, zB, out, fc_b, 250, 32000, 512, V);
}